// Round 4
// baseline (155.573 us; speedup 1.0000x reference)
//
#include <hip/hip_runtime.h>
#include <hip/hip_bf16.h>

#define DDIM 2048
#define TTIMES 256
#define NT 64                 // K-steps of 32
#define THREADS 512

typedef __attribute__((ext_vector_type(8))) short short8;
typedef __attribute__((ext_vector_type(4))) float f32x4;

using gvoid = const __attribute__((address_space(1))) void;
using svoid = __attribute__((address_space(3))) void;

__device__ __forceinline__ void gld16(const void* g, void* l) {
    __builtin_amdgcn_global_load_lds((gvoid*)g, (svoid*)l, 16, 0, 0);
}

__device__ __forceinline__ ushort f2bf(float f) {
    union { float f; unsigned int u; } v; v.f = f;
    unsigned int u = v.u;
    unsigned int r = (u + 0x7FFFu + ((u >> 16) & 1u)) >> 16;   // RNE
    return (ushort)r;
}
__device__ __forceinline__ float bf2f(ushort u) {
    union { unsigned int u; float f; } v; v.u = ((unsigned int)u) << 16;
    return v.f;
}
__device__ __forceinline__ ushort cvt1(float f) {
    union { __hip_bfloat16 h; ushort u; } cv;
    cv.h = __float2bfloat16(f);          // hardware RNE cvt
    return cv.u;
}

// ---------------- normalize org rows -> bf16 o in workspace ----------------
__global__ void norm_rows(const float* __restrict__ org, ushort* __restrict__ obf) {
    const int a   = blockIdx.x;     // time row
    const int tid = threadIdx.x;    // 256 threads
    const float* row = org + (size_t)a * DDIM;
    float4 v0 = ((const float4*)row)[tid * 2];
    float4 v1 = ((const float4*)row)[tid * 2 + 1];
    float s = v0.x*v0.x + v0.y*v0.y + v0.z*v0.z + v0.w*v0.w
            + v1.x*v1.x + v1.y*v1.y + v1.z*v1.z + v1.w*v1.w;
    #pragma unroll
    for (int off = 1; off < 64; off <<= 1) s += __shfl_xor(s, off);
    __shared__ float wsum[4];
    const int lane = tid & 63, w = tid >> 6;
    if (lane == 0) wsum[w] = s;
    __syncthreads();
    const float tot = wsum[0] + wsum[1] + wsum[2] + wsum[3];
    const float scale = 1.0f / fmaxf(sqrtf(tot), 1e-12f);
    union { ushort u[8]; uint4 v; } pk;
    pk.u[0] = f2bf(v0.x * scale); pk.u[1] = f2bf(v0.y * scale);
    pk.u[2] = f2bf(v0.z * scale); pk.u[3] = f2bf(v0.w * scale);
    pk.u[4] = f2bf(v1.x * scale); pk.u[5] = f2bf(v1.y * scale);
    pk.u[6] = f2bf(v1.z * scale); pk.u[7] = f2bf(v1.w * scale);
    ((uint4*)(obf + (size_t)a * DDIM))[tid] = pk.v;
}

// ---- triple-buffered, depth-2 prefetch, 1 barrier/step GEMM + fused trace ----
// Block: 512 thr = 8 waves (2 wm x 4 wn). Tile: 128 rows x 256 times x BK=32.
// A: global fp32 -> regs -> cvt bf16 -> swizzled ds_write (8 KB/step).
// B: gload_lds direct, linear dest + pre-swizzled source (16 KB/step).
// LDS 3 x 24 KB = 72 KB -> 2 blocks/CU. Swizzle chunk^=(row>>1)&3: 2-way (free).
__global__ __launch_bounds__(THREADS, 4) void gemm_trace(
    const float* __restrict__ x, const ushort* __restrict__ obf,
    float* __restrict__ part)
{
    __shared__ __align__(16) ushort Ab[3][4096];   // 3 x 8 KB  (128 rows x 32 k bf16)
    __shared__ __align__(16) ushort Bb[3][8192];   // 3 x 16 KB (256 rows x 32 k bf16)

    const int tid  = threadIdx.x;
    const int lane = tid & 63;
    const int wid  = tid >> 6;      // 0..7
    const int wm   = wid >> 2;      // 0..1 (row half)
    const int wn   = wid & 3;       // 0..3 (time quarter)
    const int rb   = blockIdx.x;    // 0..15 (row block of 128)
    const int d    = blockIdx.y;    // 0..31 (batch)

    // ---- A staging: thread owns (row = tid>>2, 16B-chunk = tid&3) ----
    const int arow = tid >> 2, achk = tid & 3;
    const float* as = x + (size_t)d * DDIM * DDIM
                        + (size_t)(rb * 128 + arow) * DDIM + achk * 8;
    const int awoff = arow * 32 + ((achk ^ ((arow >> 1) & 3)) * 8);  // ushort units

    // ---- B staging: linear dest, source chunk pre-swizzled ----
    const ushort* bs0 = obf + (size_t)(tid >> 2) * DDIM
                            + ((achk ^ ((tid >> 3) & 3)) * 8);
    const ushort* bs1 = bs0 + (size_t)128 * DDIM;   // rows 128..255, same swizzle bits

    // ---- fragment read offsets (swizzled) ----
    const int lr = lane & 15, lq = lane >> 4;
    const int kx = (lq ^ ((lr >> 1) & 3)) * 8;
    int aoff[4], boff[4];
    #pragma unroll
    for (int mi = 0; mi < 4; ++mi) aoff[mi] = (wm * 64 + mi * 16 + lr) * 32 + kx;
    #pragma unroll
    for (int ni = 0; ni < 4; ++ni) boff[ni] = (wn * 64 + ni * 16 + lr) * 32 + kx;

    f32x4 acc[4][4];
    #pragma unroll
    for (int mi = 0; mi < 4; ++mi)
        #pragma unroll
        for (int ni = 0; ni < 4; ++ni)
            acc[mi][ni] = (f32x4){0.f, 0.f, 0.f, 0.f};

    float4 p0, p1, q0, q1;   // two in-flight A register sets (static names, rule #20)

#define STAGE_B(t, buf) do {                                   \
    gld16(bs0 + (size_t)(t) * 32, &Bb[buf][tid * 8]);          \
    gld16(bs1 + (size_t)(t) * 32, &Bb[buf][(tid + 512) * 8]);  \
} while (0)

#define LOAD_A(t, r0, r1) do {                                 \
    r0 = *(const float4*)(as + (size_t)(t) * 32);              \
    r1 = *(const float4*)(as + (size_t)(t) * 32 + 4);          \
} while (0)

#define WRITE_A(r0, r1, buf) do {                              \
    union { ushort u[8]; uint4 v; } pk_;                       \
    pk_.u[0] = cvt1(r0.x); pk_.u[1] = cvt1(r0.y);              \
    pk_.u[2] = cvt1(r0.z); pk_.u[3] = cvt1(r0.w);              \
    pk_.u[4] = cvt1(r1.x); pk_.u[5] = cvt1(r1.y);              \
    pk_.u[6] = cvt1(r1.z); pk_.u[7] = cvt1(r1.w);              \
    *(uint4*)&Ab[buf][awoff] = pk_.v;                          \
} while (0)

#define COMPUTE(buf) do {                                                   \
    short8 af[4], bfr[4];                                                   \
    _Pragma("unroll")                                                       \
    for (int mi = 0; mi < 4; ++mi)                                          \
        af[mi] = *(const short8*)&Ab[buf][aoff[mi]];                        \
    _Pragma("unroll")                                                       \
    for (int ni = 0; ni < 4; ++ni)                                          \
        bfr[ni] = *(const short8*)&Bb[buf][boff[ni]];                       \
    _Pragma("unroll")                                                       \
    for (int mi = 0; mi < 4; ++mi)                                          \
        _Pragma("unroll")                                                   \
        for (int ni = 0; ni < 4; ++ni)                                      \
            acc[mi][ni] = __builtin_amdgcn_mfma_f32_16x16x32_bf16(          \
                af[mi], bfr[ni], acc[mi][ni], 0, 0, 0);                     \
} while (0)

#define VMW4 do { asm volatile("s_waitcnt vmcnt(4)" ::: "memory");          \
                  __builtin_amdgcn_sched_barrier(0); } while (0)
#define VMW0 do { asm volatile("s_waitcnt vmcnt(0)" ::: "memory");          \
                  __builtin_amdgcn_sched_barrier(0); } while (0)
#define BARRIER_SEQ do {                                                    \
    __builtin_amdgcn_sched_barrier(0);                                      \
    asm volatile("s_waitcnt lgkmcnt(0)" ::: "memory");                      \
    __builtin_amdgcn_s_barrier();                                           \
    __builtin_amdgcn_sched_barrier(0); } while (0)

    // ---- prologue: stage tiles 0,1; write A0 ----
    STAGE_B(0, 0); LOAD_A(0, p0, p1);
    STAGE_B(1, 1); LOAD_A(1, q0, q1);
    VMW4;                          // B0 + A0 complete (B1,A1 remain in flight)
    WRITE_A(p0, p1, 0);
    BARRIER_SEQ;

    #pragma unroll 1
    for (int i = 0; i < 31; ++i) {
        const int t  = 2 * i;
        const int b0 = t % 3, b1 = (t + 1) % 3, b2 = (t + 2) % 3;
        // even step t: compute b0; stage tile t+2; finish staging t+1
        STAGE_B(t + 2, b2); LOAD_A(t + 2, p0, p1);
        VMW4;                      // B[t+1] + A[t+1](q) complete
        WRITE_A(q0, q1, b1);
        COMPUTE(b0);
        BARRIER_SEQ;
        // odd step t+1: compute b1; stage tile t+3; finish staging t+2
        STAGE_B(t + 3, b0); LOAD_A(t + 3, q0, q1);   // (t+3)%3 == b0 (free since barrier)
        VMW4;                      // B[t+2] + A[t+2](p) complete
        WRITE_A(p0, p1, b2);
        COMPUTE(b1);
        BARRIER_SEQ;
    }
    // t = 62: outstanding = B63 + A63(q)
    VMW0;
    WRITE_A(q0, q1, 0);            // 63 % 3 == 0
    COMPUTE(2);                    // 62 % 3
    BARRIER_SEQ;
    // t = 63
    COMPUTE(0);
    __syncthreads();

#undef STAGE_B
#undef LOAD_A
#undef WRITE_A
#undef COMPUTE
#undef VMW4
#undef VMW0
#undef BARRIER_SEQ

    // ---- fused trace epilogue ----
    // acc[mi][ni][j]: row = rb*128 + wm*64 + mi*16 + lq*4 + j, time = wn*64 + ni*16 + lr
    float* plds = (float*)&Ab[0][0];   // 2 x 256 floats

    #pragma unroll
    for (int ni = 0; ni < 4; ++ni) {
        const int a_idx = wn * 64 + ni * 16 + lr;
        float ps = 0.f;
        #pragma unroll
        for (int mi = 0; mi < 4; ++mi) {
            const int bg = rb * 128 + wm * 64 + mi * 16 + lq * 4;
            const ushort4 w = *(const ushort4*)(obf + (size_t)a_idx * DDIM + bg);
            ps += bf2f(w.x) * acc[mi][ni][0];
            ps += bf2f(w.y) * acc[mi][ni][1];
            ps += bf2f(w.z) * acc[mi][ni][2];
            ps += bf2f(w.w) * acc[mi][ni][3];
        }
        ps += __shfl_xor(ps, 16);
        ps += __shfl_xor(ps, 32);
        if (lane < 16) plds[wm * 256 + a_idx] = ps;
    }
    __syncthreads();
    if (tid < 256)
        part[((size_t)d * 16 + rb) * TTIMES + tid] = plds[tid] + plds[256 + tid];
}

// ---------------- final reduce over row-blocks ----------------
__global__ void reduce_part(const float* __restrict__ part, float* __restrict__ out) {
    const int d = blockIdx.x;    // 32
    const int a = threadIdx.x;   // 256
    float s = 0.f;
    #pragma unroll
    for (int rb = 0; rb < 16; ++rb)
        s += part[((size_t)d * 16 + rb) * TTIMES + a];
    out[(size_t)d * TTIMES + a] = s;
}

extern "C" void kernel_launch(void* const* d_in, const int* in_sizes, int n_in,
                              void* d_out, int out_size, void* d_ws, size_t ws_size,
                              hipStream_t stream) {
    const float* x   = (const float*)d_in[0];   // (32, 2048, 2048) fp32
    const float* org = (const float*)d_in[1];   // (256, 2048) fp32
    float* out = (float*)d_out;                 // (32, 256) fp32

    ushort* obf = (ushort*)d_ws;                          // 1 MiB bf16 normalized o
    float*  prt = (float*)((char*)d_ws + (1 << 20));      // 512 KiB partials (32x16x256)

    norm_rows<<<dim3(TTIMES), dim3(256), 0, stream>>>(org, obf);
    gemm_trace<<<dim3(16, 32), dim3(THREADS), 0, stream>>>(x, obf, prt);
    reduce_part<<<dim3(32), dim3(256), 0, stream>>>(prt, out);
}